// Round 3
// baseline (104.472 us; speedup 1.0000x reference)
//
#include <hip/hip_runtime.h>
#include <hip/hip_bf16.h>

typedef __attribute__((ext_vector_type(4))) float f32x4;
typedef __attribute__((ext_vector_type(8))) short bf16x8;
typedef __attribute__((ext_vector_type(2))) unsigned u32x2;

#define S_LEN 4096
#define HEAD_D 64
#define WIN 256
#define QBLK 128
#define KVBLK 32
#define KSTR 72   // K row stride (shorts): 144B, b128 reads conflict-free
#define VSTR 40   // Vt row stride (shorts): 80B, 16B-aligned, b128 reads conflict-free
#define PSTR 40   // P row stride (shorts)
#define M_SHIFT 11.54156509f   // 8 * log2(e): fixed softmax shift (exp2 domain)
#define QSCALE 0.18033688f     // log2(e)/8 folded into Q

static __device__ __forceinline__ short f2bf(float f) {
  unsigned u = __builtin_bit_cast(unsigned, f);
  u += 0x7fffu + ((u >> 16) & 1u);   // RNE bf16 (inputs finite)
  return (short)(u >> 16);
}
static __device__ __forceinline__ unsigned pack2(float a, float b) {
  return (unsigned)(unsigned short)f2bf(a) | ((unsigned)(unsigned short)f2bf(b) << 16);
}

__global__ __launch_bounds__(512, 8)
void swa_fwd(const float* __restrict__ Q, const float* __restrict__ K,
             const float* __restrict__ V, float* __restrict__ O) {
  __shared__ __attribute__((aligned(16))) short k_lds[2][KVBLK * KSTR];
  __shared__ __attribute__((aligned(16))) short vt_lds[2][HEAD_D * VSTR];
  __shared__ __attribute__((aligned(16))) short p_lds[8 * 16 * PSTR];

  const int tid  = threadIdx.x;
  const int widx = tid >> 6;
  const int lane = tid & 63;
  const int lg   = lane >> 4;
  const int lc   = lane & 15;

  // XCD swizzle: 4 contiguous bh per XCD so each XCD's L2 sees a small K/V set.
  const int pb  = blockIdx.x;
  const int bh  = (pb & 7) * 4 + ((pb >> 3) >> 5);
  const int qb  = (pb >> 3) & 31;
  const int bq0 = qb * QBLK;
  const int q0w = bq0 + widx * 16;

  const size_t base = (size_t)bh * S_LEN * HEAD_D;
  const float* Qp = Q + base;
  const float* Kp = K + base;
  const float* Vp = V + base;
  float*       Op = O + base;

  // staging assignment (one f32x4 each for K and V per thread)
  const int krow = tid >> 4;          // 0..31
  const int kc4  = (tid & 15) << 2;   // 0..60
  const int vrow = tid & 31;          // 0..31
  const int vc4  = (tid >> 5) << 2;   // 0..60

  // ---- Q A-fragments, scaled by log2e/8 ----
  bf16x8 aq[2];
  {
    const float* qrow = Qp + (size_t)(q0w + lc) * HEAD_D + lg * 8;
    #pragma unroll
    for (int h = 0; h < 2; ++h) {
      f32x4 x0 = *(const f32x4*)(qrow + h * 32);
      f32x4 x1 = *(const f32x4*)(qrow + h * 32 + 4);
      bf16x8 a;
      #pragma unroll
      for (int j = 0; j < 4; ++j) {
        a[j]     = f2bf(x0[j] * QSCALE);
        a[j + 4] = f2bf(x1[j] * QSCALE);
      }
      aq[h] = a;
    }
  }

  f32x4 acc[4];
  float lreg[4];
  #pragma unroll
  for (int n = 0; n < 4; ++n) acc[n] = (f32x4){0.f, 0.f, 0.f, 0.f};
  #pragma unroll
  for (int r = 0; r < 4; ++r) lreg[r] = 0.f;

  const int lo = max(0, bq0 - WIN);
  const int hi = min(S_LEN, bq0 + QBLK + WIN);
  const int ntiles = (hi - lo) >> 5;   // all tile bounds are multiples of 32, in [0,S)

  // ---- prologue: stage tile 0 into buffer 0 ----
  {
    f32x4 kx = *(const f32x4*)(Kp + (size_t)(lo + krow) * HEAD_D + kc4);
    f32x4 vx = *(const f32x4*)(Vp + (size_t)(lo + vrow) * HEAD_D + vc4);
    *(u32x2*)&k_lds[0][krow * KSTR + kc4] = (u32x2){pack2(kx[0], kx[1]), pack2(kx[2], kx[3])};
    #pragma unroll
    for (int c = 0; c < 4; ++c) vt_lds[0][(vc4 + c) * VSTR + vrow] = f2bf(vx[c]);
  }
  __syncthreads();

  int cur = 0;
  short* const pw = &p_lds[(widx * 16) * PSTR];

  for (int t = 0; t < ntiles; ++t) {
    const int kv0 = lo + (t << 5);
    const bool more = (t + 1 < ntiles);

    // issue next-tile global loads BEFORE compute (latency hides under tile t)
    f32x4 kx, vx;
    if (more) {
      kx = *(const f32x4*)(Kp + (size_t)(kv0 + KVBLK + krow) * HEAD_D + kc4);
      vx = *(const f32x4*)(Vp + (size_t)(kv0 + KVBLK + vrow) * HEAD_D + vc4);
    }

    const short* kb = k_lds[cur];
    const short* vb = vt_lds[cur];

    // ---- S' = (Q*log2e/8) K^T : 16 q rows x 32 keys ----
    f32x4 sacc[2];
    sacc[0] = (f32x4){0.f, 0.f, 0.f, 0.f};
    sacc[1] = (f32x4){0.f, 0.f, 0.f, 0.f};
    #pragma unroll
    for (int kt = 0; kt < 2; ++kt) {
      #pragma unroll
      for (int h = 0; h < 2; ++h) {
        bf16x8 bk = *(const bf16x8*)&kb[(kt * 16 + lc) * KSTR + h * 32 + lg * 8];
        sacc[kt] = __builtin_amdgcn_mfma_f32_16x16x32_bf16(aq[h], bk, sacc[kt], 0, 0, 0);
      }
    }

    // ---- softmax numerator, fixed shift (sum reduction deferred to epilogue) ----
    const bool full = (kv0 - bq0 >= -128) && (kv0 - bq0 <= 224);  // band holds for whole block
    if (full) {
      #pragma unroll
      for (int r = 0; r < 4; ++r) {
        const float p0 = exp2f(sacc[0][r] - M_SHIFT);
        const float p1 = exp2f(sacc[1][r] - M_SHIFT);
        lreg[r] += p0 + p1;
        short* prow = pw + (lg * 4 + r) * PSTR;
        prow[lc]      = f2bf(p0);
        prow[16 + lc] = f2bf(p1);
      }
    } else {
      const int ki0 = kv0 + lc;   // staged keys always in [0,S): band mask only
      #pragma unroll
      for (int r = 0; r < 4; ++r) {
        const int qi = q0w + lg * 4 + r;
        const bool m0 = (ki0 >= qi - WIN) && (ki0 <= qi + WIN);
        const bool m1 = (ki0 + 16 >= qi - WIN) && (ki0 + 16 <= qi + WIN);
        const float p0 = m0 ? exp2f(sacc[0][r] - M_SHIFT) : 0.f;
        const float p1 = m1 ? exp2f(sacc[1][r] - M_SHIFT) : 0.f;
        lreg[r] += p0 + p1;
        short* prow = pw + (lg * 4 + r) * PSTR;
        prow[lc]      = f2bf(p0);
        prow[16 + lc] = f2bf(p1);
      }
    }

    // order same-wave P ds_writes before ds_reads (guide rule #18)
    __asm__ volatile("s_waitcnt lgkmcnt(0)" ::: "memory");
    __builtin_amdgcn_sched_barrier(0);

    // ---- PV: A = P (16x32), B = V^T (32 keys x 64 d) ----
    const bf16x8 pa = *(const bf16x8*)&p_lds[(widx * 16 + lc) * PSTR + lg * 8];
    #pragma unroll
    for (int n = 0; n < 4; ++n) {
      bf16x8 bv = *(const bf16x8*)&vb[(n * 16 + lc) * VSTR + lg * 8];
      acc[n] = __builtin_amdgcn_mfma_f32_16x16x32_bf16(pa, bv, acc[n], 0, 0, 0);
    }

    // ---- stage tile t+1 into the other buffer (compiler waits vmcnt for kx/vx) ----
    if (more) {
      short* kbn = k_lds[cur ^ 1];
      short* vbn = vt_lds[cur ^ 1];
      *(u32x2*)&kbn[krow * KSTR + kc4] = (u32x2){pack2(kx[0], kx[1]), pack2(kx[2], kx[3])};
      #pragma unroll
      for (int c = 0; c < 4; ++c) vbn[(vc4 + c) * VSTR + vrow] = f2bf(vx[c]);
    }

    // single barrier per tile: publishes tile t+1, and guards buf[cur] reuse
    // (this wave's buf[cur] reads drained by its own lgkmcnt at the barrier)
    __syncthreads();
    cur ^= 1;
  }

  // ---- epilogue: reduce denominator across the 16 key-lanes, then O = acc / l ----
  #pragma unroll
  for (int r = 0; r < 4; ++r) {
    float rs = lreg[r];
    rs += __shfl_xor(rs, 1);
    rs += __shfl_xor(rs, 2);
    rs += __shfl_xor(rs, 4);
    rs += __shfl_xor(rs, 8);
    const float inv = 1.0f / rs;
    float* orow = Op + (size_t)(q0w + lg * 4 + r) * HEAD_D;
    #pragma unroll
    for (int n = 0; n < 4; ++n) orow[n * 16 + lc] = acc[n][r] * inv;
  }
}

extern "C" void kernel_launch(void* const* d_in, const int* in_sizes, int n_in,
                              void* d_out, int out_size, void* d_ws, size_t ws_size,
                              hipStream_t stream) {
  const float* q = (const float*)d_in[0];
  const float* k = (const float*)d_in[1];
  const float* v = (const float*)d_in[2];
  float* o = (float*)d_out;
  const int blocks = 2 * 16 * (S_LEN / QBLK);  // 1024
  swa_fwd<<<dim3(blocks), dim3(512), 0, stream>>>(q, k, v, o);
}

// Round 4
// 100.053 us; speedup vs baseline: 1.0442x; 1.0442x over previous
//
#include <hip/hip_runtime.h>
#include <hip/hip_bf16.h>

typedef __attribute__((ext_vector_type(4)))  float f32x4;
typedef __attribute__((ext_vector_type(16))) float f32x16;
typedef __attribute__((ext_vector_type(8)))  short bf16x8;
typedef __attribute__((ext_vector_type(4)))  short s16x4;

#define S_LEN 4096
#define HEAD_D 64
#define WIN 256
#define QBLK 256
#define KVBLK 64
#define KSTR 72   // k_lds row stride (shorts): 144B -> b128 reads start-bank 4c%32, conflict-free
#define VSTR 72   // vt_lds row stride (shorts): b64-pair reads conflict-free
#define M_SHIFT 11.54156509f   // 8 * log2(e): fixed softmax shift in exp2 domain
#define QSCALE  0.18033688f    // log2(e)/8 folded into Q

static __device__ __forceinline__ short f2bf(float f) {
  unsigned u = __builtin_bit_cast(unsigned, f);
  u += 0x7fffu + ((u >> 16) & 1u);   // RNE bf16 (inputs finite)
  return (short)(u >> 16);
}

__global__ __launch_bounds__(512, 4)
void swa_fwd(const float* __restrict__ Q, const float* __restrict__ K,
             const float* __restrict__ V, float* __restrict__ O) {
  __shared__ __attribute__((aligned(16))) short k_lds[KVBLK * KSTR];   // 9216 B
  __shared__ __attribute__((aligned(16))) short vt_lds[HEAD_D * VSTR]; // 9216 B, [d][key]
  __shared__ float linv_lds[8 * 32];                                   // 1 KB

  const int tid  = threadIdx.x;
  const int widx = tid >> 6;
  const int lane = tid & 63;
  const int hi   = lane >> 5;   // 0/1 half of wave
  const int c    = lane & 31;   // mfma row/col lane index

  // XCD swizzle: 512 blocks; xcd = pb&7; 4 contiguous bh per XCD, qb fastest.
  const int pb  = blockIdx.x;
  const int bh  = (pb & 7) * 4 + ((pb >> 3) >> 4);
  const int qb  = (pb >> 3) & 15;
  const int bq0 = qb * QBLK;
  const int q0w = bq0 + widx * 32;   // this wave's 32 query rows

  const size_t base = (size_t)bh * S_LEN * HEAD_D;
  const float* Qp = Q + base;
  const float* Kp = K + base;
  const float* Vp = V + base;
  float*       Op = O + base;

  const f32x16 Z16 = {0.f,0.f,0.f,0.f,0.f,0.f,0.f,0.f,0.f,0.f,0.f,0.f,0.f,0.f,0.f,0.f};

  // ---- Q B-fragments (lane holds Q[q0w+c][16*d4 + 8*hi .. +7], scaled) ----
  bf16x8 aq[4];
  {
    const float* qr = Qp + (size_t)(q0w + c) * HEAD_D + hi * 8;
    #pragma unroll
    for (int d4 = 0; d4 < 4; ++d4) {
      f32x4 x0 = *(const f32x4*)(qr + d4 * 16);
      f32x4 x1 = *(const f32x4*)(qr + d4 * 16 + 4);
      bf16x8 a;
      #pragma unroll
      for (int j = 0; j < 4; ++j) { a[j] = f2bf(x0[j] * QSCALE); a[4 + j] = f2bf(x1[j] * QSCALE); }
      aq[d4] = a;
    }
  }

  f32x16 acc0 = Z16, acc1 = Z16;   // O[q][d] d-tiles 0-31 / 32-63
  float lsum = 0.f;                // denominator partial (q = c, keys of this hi-half)

  const int lo  = max(0, bq0 - WIN);
  const int khi = min(S_LEN, bq0 + QBLK + WIN);
  const int nt  = (khi - lo) >> 6;   // all bounds multiples of 64, keys always in [0,S)

  // staging assignment: K row-major b128 write; V transposed b16 writes (key-major lanes)
  const int krow = tid >> 3;          // 0..63
  const int kc   = (tid & 7) << 3;    // 0..56
  const int vkey = tid & 63;          // 0..63
  const int vd   = (tid >> 6) << 3;   // 0..56
  const float* kro = Kp + (size_t)krow * HEAD_D + kc;
  const float* vro = Vp + (size_t)vkey * HEAD_D + vd;

  for (int t = 0; t < nt; ++t) {
    const int kv0 = lo + (t << 6);

    __syncthreads();   // protect LDS vs previous tile's readers
    {
      const float* kp = kro + (size_t)kv0 * HEAD_D;
      const float* vp = vro + (size_t)kv0 * HEAD_D;
      f32x4 a0 = *(const f32x4*)kp;
      f32x4 a1 = *(const f32x4*)(kp + 4);
      f32x4 b0 = *(const f32x4*)vp;
      f32x4 b1 = *(const f32x4*)(vp + 4);
      bf16x8 kp8;
      #pragma unroll
      for (int j = 0; j < 4; ++j) { kp8[j] = f2bf(a0[j]); kp8[4 + j] = f2bf(a1[j]); }
      *(bf16x8*)&k_lds[krow * KSTR + kc] = kp8;
      #pragma unroll
      for (int j = 0; j < 4; ++j) vt_lds[(vd + j) * VSTR + vkey]     = f2bf(b0[j]);
      #pragma unroll
      for (int j = 0; j < 4; ++j) vt_lds[(vd + 4 + j) * VSTR + vkey] = f2bf(b1[j]);
    }
    __syncthreads();

    // ---- T = K · Q^T (swapped): lane holds T[key(g,hi)][q=c]; key = (g&3)+8*(g>>2)+4*hi (+32 for s1)
    f32x16 s0 = Z16, s1 = Z16;
    #pragma unroll
    for (int d4 = 0; d4 < 4; ++d4) {
      bf16x8 ak0 = *(const bf16x8*)&k_lds[c * KSTR        + d4 * 16 + hi * 8];
      bf16x8 ak1 = *(const bf16x8*)&k_lds[(32 + c) * KSTR + d4 * 16 + hi * 8];
      s0 = __builtin_amdgcn_mfma_f32_32x32x16_bf16(ak0, aq[d4], s0, 0, 0, 0);
      s1 = __builtin_amdgcn_mfma_f32_32x32x16_bf16(ak1, aq[d4], s1, 0, 0, 0);
    }

    // ---- softmax numerator: fixed shift, select-to-zero mask on edge tiles ----
    const int relw = kv0 - q0w;
    if (relw >= -224 && relw <= 192) {   // band holds for all 32 q x 64 keys of this wave
      #pragma unroll
      for (int g = 0; g < 16; ++g) {
        const float p0 = exp2f(s0[g] - M_SHIFT);
        const float p1 = exp2f(s1[g] - M_SHIFT);
        s0[g] = p0; s1[g] = p1;
        lsum += p0 + p1;
      }
    } else {
      const int kb0 = kv0 + 4 * hi - (q0w + c) + WIN;   // key - q + WIN at rowoff 0
      #pragma unroll
      for (int g = 0; g < 16; ++g) {
        const int ro = (g & 3) + 8 * (g >> 2);
        const float p0 = ((unsigned)(kb0 + ro)      <= 2u * WIN) ? exp2f(s0[g] - M_SHIFT) : 0.f;
        const float p1 = ((unsigned)(kb0 + ro + 32) <= 2u * WIN) ? exp2f(s1[g] - M_SHIFT) : 0.f;
        s0[g] = p0; s1[g] = p1;
        lsum += p0 + p1;
      }
    }

    // ---- PV: A-frag for k-chunk ka is exactly regs [8*(ka&1) .. +7] of s0/s1 (bijection
    //      with C/D layout); B-frag = V[16ka+4hi + {0..3, 8..11}][dcol] via two b64 reads ----
    #pragma unroll
    for (int ka = 0; ka < 4; ++ka) {
      bf16x8 pa;
      #pragma unroll
      for (int j = 0; j < 8; ++j) {
        const float pv = (ka & 2) ? s1[(ka & 1) * 8 + j] : s0[(ka & 1) * 8 + j];
        pa[j] = f2bf(pv);
      }
      const short* vr0 = &vt_lds[c * VSTR + ka * 16 + hi * 4];
      s16x4 l0 = *(const s16x4*)vr0;
      s16x4 h0 = *(const s16x4*)(vr0 + 8);
      bf16x8 bv0 = __builtin_shufflevector(l0, h0, 0, 1, 2, 3, 4, 5, 6, 7);
      acc0 = __builtin_amdgcn_mfma_f32_32x32x16_bf16(pa, bv0, acc0, 0, 0, 0);
      const short* vr1 = vr0 + 32 * VSTR;
      s16x4 l1 = *(const s16x4*)vr1;
      s16x4 h1 = *(const s16x4*)(vr1 + 8);
      bf16x8 bv1 = __builtin_shufflevector(l1, h1, 0, 1, 2, 3, 4, 5, 6, 7);
      acc1 = __builtin_amdgcn_mfma_f32_32x32x16_bf16(pa, bv1, acc1, 0, 0, 0);
    }
  }

  // ---- epilogue: full denominator, broadcast inverse via per-wave LDS, write O ----
  const float ltot = lsum + __shfl_xor(lsum, 32);
  if (hi == 0) linv_lds[widx * 32 + c] = 1.0f / ltot;
  __asm__ volatile("s_waitcnt lgkmcnt(0)" ::: "memory");   // same-wave write->read (rule #18)
  __builtin_amdgcn_sched_barrier(0);
  #pragma unroll
  for (int g = 0; g < 16; ++g) {
    const int qrow = (g & 3) + 8 * (g >> 2) + 4 * hi;
    const float iv = linv_lds[widx * 32 + qrow];   // phase-uniform -> LDS broadcast
    float* orow = Op + (size_t)(q0w + qrow) * HEAD_D;
    orow[c]      = acc0[g] * iv;
    orow[32 + c] = acc1[g] * iv;
  }
}

extern "C" void kernel_launch(void* const* d_in, const int* in_sizes, int n_in,
                              void* d_out, int out_size, void* d_ws, size_t ws_size,
                              hipStream_t stream) {
  const float* q = (const float*)d_in[0];
  const float* k = (const float*)d_in[1];
  const float* v = (const float*)d_in[2];
  float* o = (float*)d_out;
  const int blocks = 2 * 16 * (S_LEN / QBLK);  // 512: one per (b,h,256-row q tile)
  swa_fwd<<<dim3(blocks), dim3(512), 0, stream>>>(q, k, v, o);
}

// Round 5
// 60.349 us; speedup vs baseline: 1.7311x; 1.6579x over previous
//
#include <hip/hip_runtime.h>
#include <hip/hip_bf16.h>

typedef __attribute__((ext_vector_type(4)))  float f32x4;
typedef __attribute__((ext_vector_type(16))) float f32x16;
typedef __attribute__((ext_vector_type(8)))  short bf16x8;
typedef __attribute__((ext_vector_type(4)))  short s16x4;

#define S_LEN 4096
#define HEAD_D 64
#define WIN 256
#define QBLK 128
#define KVBLK 64
#define KSTR 72   // k_lds row stride (shorts), 144B
#define VSTR 72   // vt_lds row stride (shorts), [d][key]
#define M_SHIFT 11.54156509f   // 8 * log2(e): fixed softmax shift (exp2 domain)
#define QSCALE  0.18033688f    // log2(e)/8 folded into Q

static __device__ __forceinline__ short f2bf(float f) {
  unsigned u = __builtin_bit_cast(unsigned, f);
  u += 0x7fffu + ((u >> 16) & 1u);   // RNE bf16 (inputs finite)
  return (short)(u >> 16);
}

__global__ __launch_bounds__(512, 4)
void swa_fwd(const float* __restrict__ Q, const float* __restrict__ K,
             const float* __restrict__ V, float* __restrict__ O) {
  __shared__ __attribute__((aligned(16))) short k_lds[KVBLK * KSTR];   // 9216 B
  __shared__ __attribute__((aligned(16))) short vt_lds[HEAD_D * VSTR]; // 9216 B
  __shared__ __attribute__((aligned(16))) float o_lds[4][32][HEAD_D];  // 32 KB (epilogue merge)
  __shared__ float l_lds[4][2][32];                                    // 1 KB

  const int tid  = threadIdx.x;
  const int widx = tid >> 6;
  const int lane = tid & 63;
  const int hi   = lane >> 5;
  const int c    = lane & 31;
  const int qg   = widx & 3;    // q-group: 32 rows
  const int kh   = widx >> 2;   // key half of each 64-key tile
  const int kho  = kh * 32;

  // XCD swizzle (R2's): 4 contiguous bh per XCD, qb fastest -> neighbor-qb L2 reuse.
  const int pb  = blockIdx.x;
  const int bh  = (pb & 7) * 4 + ((pb >> 3) >> 5);
  const int qb  = (pb >> 3) & 31;
  const int bq0 = qb * QBLK;
  const int q0w = bq0 + qg * 32;

  const size_t base = (size_t)bh * S_LEN * HEAD_D;
  const float* Qp = Q + base;
  const float* Kp = K + base;
  const float* Vp = V + base;
  float*       Op = O + base;

  const f32x16 Z16 = {0.f,0.f,0.f,0.f,0.f,0.f,0.f,0.f,0.f,0.f,0.f,0.f,0.f,0.f,0.f,0.f};

  // ---- Q B-fragments: lane holds Q[q0w+c][ch*16 + hi*8 + j]*QSCALE ----
  bf16x8 aq[4];
  {
    const float* qr = Qp + (size_t)(q0w + c) * HEAD_D + hi * 8;
    #pragma unroll
    for (int ch = 0; ch < 4; ++ch) {
      f32x4 x0 = *(const f32x4*)(qr + ch * 16);
      f32x4 x1 = *(const f32x4*)(qr + ch * 16 + 4);
      bf16x8 a;
      #pragma unroll
      for (int j = 0; j < 4; ++j) { a[j] = f2bf(x0[j] * QSCALE); a[4 + j] = f2bf(x1[j] * QSCALE); }
      aq[ch] = a;
    }
  }

  f32x16 acc0 = Z16, acc1 = Z16;   // O-partial [32q x d0-31 / d32-63] for this key-half
  float lsum = 0.f;

  const int lo   = max(0, bq0 - WIN);
  const int khiB = min(S_LEN, bq0 + QBLK + WIN);
  const int nt   = (khiB - lo) >> 6;   // bounds are multiples of 64; keys always in [0,S)

  // staging: K coalesced rows (8 lanes per row); V segment-covering transposed writes
  const int krow = tid >> 3;          // 0..63
  const int kc8  = (tid & 7) << 3;    // 0..56
  const int vkey = lane;              // 0..63
  const int vd8  = widx << 3;         // 0..56
  const float* kpt = Kp + (size_t)(lo + krow) * HEAD_D + kc8;
  const float* vpt = Vp + (size_t)(lo + vkey) * HEAD_D + vd8;

  // prologue: tile 0 into registers
  f32x4 ka0 = *(const f32x4*)kpt;
  f32x4 ka1 = *(const f32x4*)(kpt + 4);
  f32x4 va0 = *(const f32x4*)vpt;
  f32x4 va1 = *(const f32x4*)(vpt + 4);
  kpt += KVBLK * HEAD_D;
  vpt += KVBLK * HEAD_D;

  for (int t = 0; t < nt; ++t) {
    const int kv0 = lo + (t << 6);

    __syncthreads();   // all reads of previous tile done -> LDS reusable
    {
      bf16x8 kp8;
      #pragma unroll
      for (int j = 0; j < 4; ++j) { kp8[j] = f2bf(ka0[j]); kp8[4 + j] = f2bf(ka1[j]); }
      *(bf16x8*)&k_lds[krow * KSTR + kc8] = kp8;
      #pragma unroll
      for (int j = 0; j < 4; ++j) vt_lds[(vd8 + j) * VSTR + vkey]     = f2bf(va0[j]);
      #pragma unroll
      for (int j = 0; j < 4; ++j) vt_lds[(vd8 + 4 + j) * VSTR + vkey] = f2bf(va1[j]);
    }
    // issue next-tile loads now (WAR on regs is ordered by dataflow); latency hides under compute
    if (t + 1 < nt) {
      ka0 = *(const f32x4*)kpt;
      ka1 = *(const f32x4*)(kpt + 4);
      va0 = *(const f32x4*)vpt;
      va1 = *(const f32x4*)(vpt + 4);
      kpt += KVBLK * HEAD_D;
      vpt += KVBLK * HEAD_D;
    }
    __syncthreads();   // publish tile t

    // ---- swapped QK: T[key][q], A = K rows (this key-half), B = Q regs ----
    f32x16 s = Z16;
    #pragma unroll
    for (int ch = 0; ch < 4; ++ch) {
      bf16x8 akf = *(const bf16x8*)&k_lds[(kho + c) * KSTR + ch * 16 + hi * 8];
      s = __builtin_amdgcn_mfma_f32_32x32x16_bf16(akf, aq[ch], s, 0, 0, 0);
    }

    // ---- fixed-shift softmax numerator; reg r holds key kv0+kho+(r&3)+8(r>>2)+4hi, q=q0w+c ----
    const int rel = kv0 + kho - q0w;
    if (rel >= -224 && rel <= 224) {   // whole 32q x 32k sub-tile inside the band
      #pragma unroll
      for (int g = 0; g < 16; ++g) {
        const float p = exp2f(s[g] - M_SHIFT);
        s[g] = p; lsum += p;
      }
    } else {
      const int bm = rel + 4 * hi - c + WIN;
      #pragma unroll
      for (int g = 0; g < 16; ++g) {
        const int ro = (g & 3) + 8 * (g >> 2);
        const float p = ((unsigned)(bm + ro) <= 2u * WIN) ? exp2f(s[g] - M_SHIFT) : 0.f;
        s[g] = p; lsum += p;
      }
    }

    // ---- PV via register-P bijection (R4-verified): A-frag slot j of chunk kt = s[kt*8+j];
    //      B-frag = V[kho + kt*16 + 4hi + {0..3, 8..11}][d] (same slot->key map) ----
    #pragma unroll
    for (int kt = 0; kt < 2; ++kt) {
      bf16x8 pa;
      #pragma unroll
      for (int j = 0; j < 8; ++j) pa[j] = f2bf(s[kt * 8 + j]);
      const int vb = kho + kt * 16 + 4 * hi;
      {
        const short* vr = &vt_lds[c * VSTR + vb];
        s16x4 a0 = *(const s16x4*)vr;
        s16x4 b0 = *(const s16x4*)(vr + 8);
        bf16x8 bv = __builtin_shufflevector(a0, b0, 0, 1, 2, 3, 4, 5, 6, 7);
        acc0 = __builtin_amdgcn_mfma_f32_32x32x16_bf16(pa, bv, acc0, 0, 0, 0);
      }
      {
        const short* vr = &vt_lds[(32 + c) * VSTR + vb];
        s16x4 a1 = *(const s16x4*)vr;
        s16x4 b1 = *(const s16x4*)(vr + 8);
        bf16x8 bv = __builtin_shufflevector(a1, b1, 0, 1, 2, 3, 4, 5, 6, 7);
        acc1 = __builtin_amdgcn_mfma_f32_32x32x16_bf16(pa, bv, acc1, 0, 0, 0);
      }
    }
  }

  // ---- epilogue: merge the two key-halves (pure adds under fixed shift) ----
  lsum += __shfl_xor(lsum, 32);           // combine hi halves (same q=c column)
  if (hi == 0) l_lds[qg][kh][c] = lsum;   // per-half denominator partial
  if (kh == 0) {
    #pragma unroll
    for (int g = 0; g < 16; ++g) {
      const int qrow = (g & 3) + 8 * (g >> 2) + 4 * hi;
      o_lds[qg][qrow][c]      = acc0[g];
      o_lds[qg][qrow][32 + c] = acc1[g];
    }
  }
  __syncthreads();
  if (kh == 1) {
    if (hi == 0) l_lds[qg][0][c] = 1.0f / (l_lds[qg][0][c] + l_lds[qg][1][c]);
    __asm__ volatile("s_waitcnt lgkmcnt(0)" ::: "memory");   // same-wave write->read (rule #18)
    __builtin_amdgcn_sched_barrier(0);
    #pragma unroll
    for (int g = 0; g < 16; ++g) {
      const int qrow = (g & 3) + 8 * (g >> 2) + 4 * hi;
      const float iv = l_lds[qg][0][qrow];   // lane-uniform row -> LDS broadcast
      float* orow = Op + (size_t)(q0w + qrow) * HEAD_D;
      orow[c]      = (o_lds[qg][qrow][c]      + acc0[g]) * iv;
      orow[32 + c] = (o_lds[qg][qrow][32 + c] + acc1[g]) * iv;
    }
  }
}

extern "C" void kernel_launch(void* const* d_in, const int* in_sizes, int n_in,
                              void* d_out, int out_size, void* d_ws, size_t ws_size,
                              hipStream_t stream) {
  const float* q = (const float*)d_in[0];
  const float* k = (const float*)d_in[1];
  const float* v = (const float*)d_in[2];
  float* o = (float*)d_out;
  const int blocks = 2 * 16 * (S_LEN / QBLK);  // 1024
  swa_fwd<<<dim3(blocks), dim3(512), 0, stream>>>(q, k, v, o);
}

// Round 6
// 54.496 us; speedup vs baseline: 1.9171x; 1.1074x over previous
//
#include <hip/hip_runtime.h>
#include <hip/hip_bf16.h>

typedef __attribute__((ext_vector_type(4)))  float f32x4;
typedef __attribute__((ext_vector_type(16))) float f32x16;
typedef __attribute__((ext_vector_type(8)))  short bf16x8;
typedef __attribute__((ext_vector_type(4)))  short s16x4;
typedef __attribute__((ext_vector_type(4)))  unsigned u32x4;

#define S_LEN 4096
#define HEAD_D 64
#define WIN 256
#define QBLK 128
#define KVBLK 64
#define KSTR 72   // k_lds row stride (shorts), 144B
#define VSTR 72   // vt_lds row stride (shorts), [d][key]
#define M_SHIFT 11.54156509f   // 8 * log2(e): fixed softmax shift (exp2 domain)
#define QSCALE  0.18033688f    // log2(e)/8 folded into Q

// HW packed f32->bf16 (RNE), 1 instr for 2 values
static __device__ __forceinline__ unsigned cvt2(float lo, float hi) {
  unsigned r;
  asm("v_cvt_pk_bf16_f32 %0, %1, %2" : "=v"(r) : "v"(lo), "v"(hi));
  return r;
}

__global__ __launch_bounds__(512, 4)
void swa_fwd(const float* __restrict__ Q, const float* __restrict__ K,
             const float* __restrict__ V, float* __restrict__ O) {
  __shared__ __attribute__((aligned(16))) short k_lds[KVBLK * KSTR];    // 9216 B
  __shared__ __attribute__((aligned(16))) short vt_lds[HEAD_D * VSTR];  // 9216 B
  __shared__ __attribute__((aligned(16))) float o_mrg[2][32][HEAD_D];   // 16 KB (2-pass merge)
  __shared__ float l_lds[4][2][32];                                     // 1 KB

  const int tid  = threadIdx.x;
  const int widx = tid >> 6;
  const int lane = tid & 63;
  const int hi   = lane >> 5;
  const int c    = lane & 31;
  const int qg   = widx & 3;    // q-group: 32 rows
  const int kh   = widx >> 2;   // key half of each 64-key tile
  const int kho  = kh * 32;

  // XCD swizzle: 4 contiguous bh per XCD, qb fastest -> neighbor-qb L2 reuse.
  const int pb  = blockIdx.x;
  const int bh  = (pb & 7) * 4 + ((pb >> 3) >> 5);
  const int qb  = (pb >> 3) & 31;
  const int bq0 = qb * QBLK;
  const int q0w = bq0 + qg * 32;

  const size_t base = (size_t)bh * S_LEN * HEAD_D;
  const float* Qp = Q + base;
  const float* Kp = K + base;
  const float* Vp = V + base;
  float*       Op = O + base;

  const f32x16 Z16 = {0.f,0.f,0.f,0.f,0.f,0.f,0.f,0.f,0.f,0.f,0.f,0.f,0.f,0.f,0.f,0.f};

  // ---- Q B-fragments: lane holds Q[q0w+c][ch*16 + hi*8 + j]*QSCALE ----
  bf16x8 aq[4];
  {
    const float* qr = Qp + (size_t)(q0w + c) * HEAD_D + hi * 8;
    #pragma unroll
    for (int ch = 0; ch < 4; ++ch) {
      f32x4 x0 = *(const f32x4*)(qr + ch * 16);
      f32x4 x1 = *(const f32x4*)(qr + ch * 16 + 4);
      u32x4 au;
      au[0] = cvt2(x0[0] * QSCALE, x0[1] * QSCALE);
      au[1] = cvt2(x0[2] * QSCALE, x0[3] * QSCALE);
      au[2] = cvt2(x1[0] * QSCALE, x1[1] * QSCALE);
      au[3] = cvt2(x1[2] * QSCALE, x1[3] * QSCALE);
      aq[ch] = __builtin_bit_cast(bf16x8, au);
    }
  }

  f32x16 acc0 = Z16, acc1 = Z16;   // O-partial [32q x d0-31 / d32-63] for this key-half
  float lsum = 0.f;

  const int lo   = max(0, bq0 - WIN);
  const int khiB = min(S_LEN, bq0 + QBLK + WIN);
  const int nt   = (khiB - lo) >> 6;   // multiples of 64; keys always in [0,S)

  // staging: K coalesced rows (8 lanes/row, b128 write);
  // V: each thread owns a KEY PAIR x 4 d -> packs 2 keys into one b32 write (banks 2-way=free)
  const int krow = tid >> 3;          // 0..63
  const int kc8  = (tid & 7) << 3;    // 0..56
  const int key2 = (tid & 31) << 1;   // 0..62 (even)
  const int vd4  = (tid >> 5) << 2;   // 0..60
  const float* kpt  = Kp + (size_t)(lo + krow) * HEAD_D + kc8;
  const float* vpt0 = Vp + (size_t)(lo + key2) * HEAD_D + vd4;
  const float* vpt1 = vpt0 + HEAD_D;

  // prologue: tile 0 into registers
  f32x4 ka0 = *(const f32x4*)kpt;
  f32x4 ka1 = *(const f32x4*)(kpt + 4);
  f32x4 va0 = *(const f32x4*)vpt0;
  f32x4 va1 = *(const f32x4*)vpt1;
  kpt  += KVBLK * HEAD_D;
  vpt0 += KVBLK * HEAD_D;
  vpt1 += KVBLK * HEAD_D;

  for (int t = 0; t < nt; ++t) {
    const int kv0 = lo + (t << 6);

    __syncthreads();   // all reads of previous tile done -> LDS reusable
    {
      u32x4 kw;
      kw[0] = cvt2(ka0[0], ka0[1]);
      kw[1] = cvt2(ka0[2], ka0[3]);
      kw[2] = cvt2(ka1[0], ka1[1]);
      kw[3] = cvt2(ka1[2], ka1[3]);
      *(u32x4*)&k_lds[krow * KSTR + kc8] = kw;
      #pragma unroll
      for (int j = 0; j < 4; ++j)
        *(unsigned*)&vt_lds[(vd4 + j) * VSTR + key2] = cvt2(va0[j], va1[j]);
    }
    // issue next-tile loads now; latency hides under this tile's compute
    if (t + 1 < nt) {
      ka0 = *(const f32x4*)kpt;
      ka1 = *(const f32x4*)(kpt + 4);
      va0 = *(const f32x4*)vpt0;
      va1 = *(const f32x4*)vpt1;
      kpt  += KVBLK * HEAD_D;
      vpt0 += KVBLK * HEAD_D;
      vpt1 += KVBLK * HEAD_D;
    }
    __syncthreads();   // publish tile t

    // ---- swapped QK: T[key][q], A = K rows (this key-half), B = Q regs ----
    f32x16 s = Z16;
    #pragma unroll
    for (int ch = 0; ch < 4; ++ch) {
      bf16x8 akf = *(const bf16x8*)&k_lds[(kho + c) * KSTR + ch * 16 + hi * 8];
      s = __builtin_amdgcn_mfma_f32_32x32x16_bf16(akf, aq[ch], s, 0, 0, 0);
    }

    // ---- fixed-shift softmax numerator; reg g holds key kv0+kho+(g&3)+8(g>>2)+4hi, q=q0w+c ----
    const int rel = kv0 + kho - q0w;
    if (rel >= -224 && rel <= 224) {   // whole 32q x 32k sub-tile inside band
      #pragma unroll
      for (int g = 0; g < 16; ++g) {
        const float p = exp2f(s[g] - M_SHIFT);
        s[g] = p; lsum += p;
      }
    } else {
      const int bm = rel + 4 * hi - c + WIN;
      #pragma unroll
      for (int g = 0; g < 16; ++g) {
        const int ro = (g & 3) + 8 * (g >> 2);
        const float p = ((unsigned)(bm + ro) <= 2u * WIN) ? exp2f(s[g] - M_SHIFT) : 0.f;
        s[g] = p; lsum += p;
      }
    }

    // ---- PV via register-P bijection: A-frag slot j of chunk kt = s[kt*8+j];
    //      B-frag = V[kho + kt*16 + 4hi + {0..3, 8..11}][d] ----
    #pragma unroll
    for (int kt = 0; kt < 2; ++kt) {
      u32x4 pau;
      #pragma unroll
      for (int p2 = 0; p2 < 4; ++p2)
        pau[p2] = cvt2(s[kt * 8 + 2 * p2], s[kt * 8 + 2 * p2 + 1]);
      const bf16x8 pa = __builtin_bit_cast(bf16x8, pau);
      const int vb = kho + kt * 16 + 4 * hi;
      {
        const short* vr = &vt_lds[c * VSTR + vb];
        s16x4 a0 = *(const s16x4*)vr;
        s16x4 b0 = *(const s16x4*)(vr + 8);
        bf16x8 bv = __builtin_shufflevector(a0, b0, 0, 1, 2, 3, 4, 5, 6, 7);
        acc0 = __builtin_amdgcn_mfma_f32_32x32x16_bf16(pa, bv, acc0, 0, 0, 0);
      }
      {
        const short* vr = &vt_lds[(32 + c) * VSTR + vb];
        s16x4 a1 = *(const s16x4*)vr;
        s16x4 b1 = *(const s16x4*)(vr + 8);
        bf16x8 bv = __builtin_shufflevector(a1, b1, 0, 1, 2, 3, 4, 5, 6, 7);
        acc1 = __builtin_amdgcn_mfma_f32_32x32x16_bf16(pa, bv, acc1, 0, 0, 0);
      }
    }
  }

  // ---- epilogue: merge key-halves (pure adds under fixed shift), 2 passes over qg pairs ----
  lsum += __shfl_xor(lsum, 32);           // combine hi halves (same q=c column)
  if (hi == 0) l_lds[qg][kh][c] = lsum;
  __syncthreads();                         // publish l partials
  if (kh == 1 && hi == 0)
    l_lds[qg][0][c] = 1.0f / (l_lds[qg][0][c] + l_lds[qg][1][c]);  // read via later barrier

  #pragma unroll
  for (int p = 0; p < 2; ++p) {
    if (p) __syncthreads();               // protect o_mrg reuse between passes
    if (kh == 0 && (qg >> 1) == p) {
      #pragma unroll
      for (int g = 0; g < 16; ++g) {
        const int qrow = (g & 3) + 8 * (g >> 2) + 4 * hi;
        o_mrg[qg & 1][qrow][c]      = acc0[g];
        o_mrg[qg & 1][qrow][32 + c] = acc1[g];
      }
    }
    __syncthreads();                      // publish partials (also drains l_lds writes)
    if (kh == 1 && (qg >> 1) == p) {
      #pragma unroll
      for (int g = 0; g < 16; ++g) {
        const int qrow = (g & 3) + 8 * (g >> 2) + 4 * hi;
        const float iv = l_lds[qg][0][qrow];   // lane-uniform -> LDS broadcast
        float* orow = Op + (size_t)(q0w + qrow) * HEAD_D;
        orow[c]      = (o_mrg[qg & 1][qrow][c]      + acc0[g]) * iv;
        orow[32 + c] = (o_mrg[qg & 1][qrow][32 + c] + acc1[g]) * iv;
      }
    }
  }
}

extern "C" void kernel_launch(void* const* d_in, const int* in_sizes, int n_in,
                              void* d_out, int out_size, void* d_ws, size_t ws_size,
                              hipStream_t stream) {
  const float* q = (const float*)d_in[0];
  const float* k = (const float*)d_in[1];
  const float* v = (const float*)d_in[2];
  float* o = (float*)d_out;
  const int blocks = 2 * 16 * (S_LEN / QBLK);  // 1024
  swa_fwd<<<dim3(blocks), dim3(512), 0, stream>>>(q, k, v, o);
}